// Round 1
// baseline (2958.699 us; speedup 1.0000x reference)
//
#include <hip/hip_runtime.h>
#include <hip/hip_bf16.h>

#define NU 30000
#define NI 70000
#define NN 100000
#define DD 128
#define NLAYERS 3
#define SLOPE_ 0.01f
#define EPS_ 1e-12f

// ---------------------------------------------------------------- concat ----
__global__ __launch_bounds__(256) void k_concat(const float4* __restrict__ u,
                                                const float4* __restrict__ it,
                                                float4* __restrict__ f,
                                                int total4, int nu4) {
    int i = blockIdx.x * 256 + threadIdx.x;
    if (i < total4) f[i] = (i < nu4) ? u[i] : it[i - nu4];
}

// ---------------------------------------------------------------- zero ------
__global__ __launch_bounds__(256) void k_zero(float4* __restrict__ p, int n4) {
    int i = blockIdx.x * 256 + threadIdx.x;
    if (i < n4) p[i] = make_float4(0.f, 0.f, 0.f, 0.f);
}

// ---------------------------------------------------------------- dot -------
// one wave per batch element; float2 per lane covers 128 dims
__global__ __launch_bounds__(256) void k_dot(const float* __restrict__ f,
                                             const int* __restrict__ uIdx,
                                             const int* __restrict__ iIdx,
                                             float* __restrict__ out,
                                             int batch, int accum) {
    int b = blockIdx.x * 4 + (threadIdx.x >> 6);
    if (b >= batch) return;
    int lane = threadIdx.x & 63;
    const float2* ur = (const float2*)(f + (size_t)uIdx[b] * DD);
    const float2* ir = (const float2*)(f + (size_t)(iIdx[b] + NU) * DD);
    float2 a = ur[lane];
    float2 c = ir[lane];
    float s = a.x * c.x + a.y * c.y;
#pragma unroll
    for (int m = 32; m; m >>= 1) s += __shfl_xor(s, m, 64);
    if (lane == 0) out[b] = accum ? out[b] + s : s;
}

// ---------------------------------------------------------------- spmm ------
// one wave per edge: Lx[row] += val * f[col]; float2 per lane, fp32 HW atomics
__global__ __launch_bounds__(256) void k_spmm(const int* __restrict__ rows,
                                              const int* __restrict__ cols,
                                              const float* __restrict__ vals,
                                              const float* __restrict__ f,
                                              float* __restrict__ Lx, int nnz) {
    int e = blockIdx.x * 4 + (threadIdx.x >> 6);
    if (e >= nnz) return;
    int lane = threadIdx.x & 63;
    int r = rows[e];
    int c = cols[e];
    float v = vals[e];
    float2 x = ((const float2*)(f + (size_t)c * DD))[lane];
    float* dst = Lx + (size_t)r * DD + lane * 2;
    unsafeAtomicAdd(dst, v * x.x);
    unsafeAtomicAdd(dst + 1, v * x.y);
}

// ---------------------------------------------------------------- layer -----
// fused: y = leakyrelu((Lx+f)@Wlin + (Lx*f)@Wint + (blin+bint)); f = y/max(||y||,eps)
// GEMM view: A = [Lx+f | Lx*f]  (N x 256), B = [Wlin ; Wint]  (256 x 128)
// BM=128, BN=128, BK=32; 256 threads; each thread 8x8 accumulators.
#define BM 128
#define BN 128
#define BK 32
#define TM 8
#define TN 8

__global__ __launch_bounds__(256) void k_layer(const float* __restrict__ Lx,
                                               const float* __restrict__ feat,
                                               const float* __restrict__ Wlin,
                                               const float* __restrict__ blin,
                                               const float* __restrict__ Wint,
                                               const float* __restrict__ bint,
                                               float* __restrict__ fout) {
    __shared__ float As[BK][BM + 4];   // stride 132 floats: rows stay 16B-aligned
    __shared__ float Bs[BK][BN];

    const int t  = threadIdx.x;
    const int tx = t & 15;   // output-dim group: j0 = tx*8
    const int ty = t >> 4;   // node group: nodes ty*8 .. ty*8+7
    const int m0 = blockIdx.x * BM;

    float acc[TM][TN] = {};

    for (int kc = 0; kc < 8; ++kc) {
        const bool addhalf = (kc < 4);
        const int gk0 = addhalf ? kc * BK : (kc - 4) * BK;

        // ---- stage A (transposed): 128 nodes x 32 k
#pragma unroll
        for (int p = 0; p < 4; ++p) {
            int idx4 = p * 256 + t;          // float4 index 0..1023
            int ml = idx4 >> 3;              // node local 0..127
            int kk = (idx4 & 7) * 4;         // k offset 0,4,..,28
            int gm = m0 + ml;
            float4 av;
            if (gm < NN) {
                const float* lp = Lx   + (size_t)gm * DD + gk0 + kk;
                const float* fp = feat + (size_t)gm * DD + gk0 + kk;
                float4 l4 = *(const float4*)lp;
                float4 f4 = *(const float4*)fp;
                if (addhalf)
                    av = make_float4(l4.x + f4.x, l4.y + f4.y, l4.z + f4.z, l4.w + f4.w);
                else
                    av = make_float4(l4.x * f4.x, l4.y * f4.y, l4.z * f4.z, l4.w * f4.w);
            } else {
                av = make_float4(0.f, 0.f, 0.f, 0.f);
            }
            As[kk + 0][ml] = av.x;
            As[kk + 1][ml] = av.y;
            As[kk + 2][ml] = av.z;
            As[kk + 3][ml] = av.w;
        }

        // ---- stage B: 32 k x 128 j
        const float* Wsrc = addhalf ? Wlin : Wint;
#pragma unroll
        for (int p = 0; p < 4; ++p) {
            int k = p * 8 + (t >> 5);
            int j = (t & 31) * 4;
            *(float4*)&Bs[k][j] = *(const float4*)(Wsrc + (size_t)(gk0 + k) * DD + j);
        }

        __syncthreads();

#pragma unroll
        for (int kk = 0; kk < BK; ++kk) {
            float4 a0 = *(const float4*)&As[kk][ty * TM];
            float4 a1 = *(const float4*)&As[kk][ty * TM + 4];
            float4 b0 = *(const float4*)&Bs[kk][tx * TN];
            float4 b1 = *(const float4*)&Bs[kk][tx * TN + 4];
            float av[TM] = {a0.x, a0.y, a0.z, a0.w, a1.x, a1.y, a1.z, a1.w};
            float bv[TN] = {b0.x, b0.y, b0.z, b0.w, b1.x, b1.y, b1.z, b1.w};
#pragma unroll
            for (int i = 0; i < TM; ++i) {
#pragma unroll
                for (int j = 0; j < TN; ++j)
                    acc[i][j] = fmaf(av[i], bv[j], acc[i][j]);
            }
        }
        __syncthreads();
    }

    // ---- epilogue: bias, leaky relu, row-normalize, store
    float bias[TN];
#pragma unroll
    for (int j = 0; j < TN; ++j) bias[j] = blin[tx * TN + j] + bint[tx * TN + j];

#pragma unroll
    for (int i = 0; i < TM; ++i) {
        float ss = 0.f;
#pragma unroll
        for (int j = 0; j < TN; ++j) {
            float v = acc[i][j] + bias[j];
            v = (v > 0.f) ? v : SLOPE_ * v;
            acc[i][j] = v;
            ss += v * v;
        }
        // reduce over the 16 lanes (same ty) that hold this node's 128 dims
#pragma unroll
        for (int m = 1; m < 16; m <<= 1) ss += __shfl_xor(ss, m, 64);
        float rinv = 1.0f / fmaxf(sqrtf(ss), EPS_);
        int gm = m0 + ty * TM + i;
        if (gm < NN) {
            float* op = fout + (size_t)gm * DD + tx * TN;
            *(float4*)op = make_float4(acc[i][0] * rinv, acc[i][1] * rinv,
                                       acc[i][2] * rinv, acc[i][3] * rinv);
            *(float4*)(op + 4) = make_float4(acc[i][4] * rinv, acc[i][5] * rinv,
                                             acc[i][6] * rinv, acc[i][7] * rinv);
        }
    }
}

// ---------------------------------------------------------------- launch ----
extern "C" void kernel_launch(void* const* d_in, const int* in_sizes, int n_in,
                              void* d_out, int out_size, void* d_ws, size_t ws_size,
                              hipStream_t stream) {
    const int*   userIdx = (const int*)d_in[0];
    const int*   itemIdx = (const int*)d_in[1];
    const int*   rows    = (const int*)d_in[2];
    const int*   cols    = (const int*)d_in[3];
    const float* vals    = (const float*)d_in[4];
    const float* uE      = (const float*)d_in[5];
    const float* iE      = (const float*)d_in[6];
    const float* Wlin    = (const float*)d_in[7];
    const float* blin    = (const float*)d_in[8];
    const float* Wint    = (const float*)d_in[9];
    const float* bint    = (const float*)d_in[10];
    float* out = (float*)d_out;

    const int batch = in_sizes[0];
    const int nnz   = in_sizes[2];

    float* feat = (float*)d_ws;                   // N*128 fp32 = 51.2 MB
    float* Lx   = feat + (size_t)NN * DD;         // N*128 fp32 = 51.2 MB

    const int total4 = NN * (DD / 4);             // 3.2M float4
    const int nu4    = NU * (DD / 4);

    k_concat<<<(total4 + 255) / 256, 256, 0, stream>>>(
        (const float4*)uE, (const float4*)iE, (float4*)feat, total4, nu4);

    k_dot<<<(batch + 3) / 4, 256, 0, stream>>>(feat, userIdx, itemIdx, out, batch, 0);

    for (int l = 0; l < NLAYERS; ++l) {
        k_zero<<<(total4 + 255) / 256, 256, 0, stream>>>((float4*)Lx, total4);
        k_spmm<<<(nnz + 3) / 4, 256, 0, stream>>>(rows, cols, vals, feat, Lx, nnz);
        k_layer<<<(NN + BM - 1) / BM, 256, 0, stream>>>(
            Lx, feat,
            Wlin + (size_t)l * DD * DD, blin + (size_t)l * DD,
            Wint + (size_t)l * DD * DD, bint + (size_t)l * DD,
            feat);
        k_dot<<<(batch + 3) / 4, 256, 0, stream>>>(feat, userIdx, itemIdx, out, batch, 1);
    }
}

// Round 2
// 917.003 us; speedup vs baseline: 3.2265x; 3.2265x over previous
//
#include <hip/hip_runtime.h>
#include <hip/hip_bf16.h>

#define NU 30000
#define NI 70000
#define NN 100000
#define DD 128
#define NLAYERS 3
#define SLOPE_ 0.01f
#define EPS_ 1e-12f

#define SCAN_CHUNK 1024                       // elems per scan block
#define SCAN_BLOCKS ((NN + SCAN_CHUNK - 1) / SCAN_CHUNK)   // 98

// ---------------------------------------------------------------- concat ----
__global__ __launch_bounds__(256) void k_concat(const float4* __restrict__ u,
                                                const float4* __restrict__ it,
                                                float4* __restrict__ f,
                                                int total4, int nu4) {
    int i = blockIdx.x * 256 + threadIdx.x;
    if (i < total4) f[i] = (i < nu4) ? u[i] : it[i - nu4];
}

// ---------------------------------------------------------------- zero ------
__global__ __launch_bounds__(256) void k_zero(float4* __restrict__ p, int n4) {
    int i = blockIdx.x * 256 + threadIdx.x;
    if (i < n4) p[i] = make_float4(0.f, 0.f, 0.f, 0.f);
}

// ---------------------------------------------------------------- dot -------
__global__ __launch_bounds__(256) void k_dot(const float* __restrict__ f,
                                             const int* __restrict__ uIdx,
                                             const int* __restrict__ iIdx,
                                             float* __restrict__ out,
                                             int batch, int accum) {
    int b = blockIdx.x * 4 + (threadIdx.x >> 6);
    if (b >= batch) return;
    int lane = threadIdx.x & 63;
    const float2* ur = (const float2*)(f + (size_t)uIdx[b] * DD);
    const float2* ir = (const float2*)(f + (size_t)(iIdx[b] + NU) * DD);
    float2 a = ur[lane];
    float2 c = ir[lane];
    float s = a.x * c.x + a.y * c.y;
#pragma unroll
    for (int m = 32; m; m >>= 1) s += __shfl_xor(s, m, 64);
    if (lane == 0) out[b] = accum ? out[b] + s : s;
}

// ---------------------------------------------------------------- CSR build -
__global__ __launch_bounds__(256) void k_hist(const int* __restrict__ rows,
                                              int* __restrict__ cnt, int nnz) {
    int e = blockIdx.x * 256 + threadIdx.x;
    if (e < nnz) atomicAdd(&cnt[rows[e]], 1);
}

// per-block sums of 1024 counts
__global__ __launch_bounds__(256) void k_scan1(const int* __restrict__ cnt,
                                               int* __restrict__ bsums) {
    int idx = blockIdx.x * SCAN_CHUNK + threadIdx.x * 4;
    int4 c = make_int4(0, 0, 0, 0);
    if (idx < NN) c = *(const int4*)(cnt + idx);      // NN % 4 == 0
    int s = c.x + c.y + c.z + c.w;
#pragma unroll
    for (int m = 1; m < 64; m <<= 1) s += __shfl_xor(s, m, 64);
    __shared__ int ws[4];
    if ((threadIdx.x & 63) == 0) ws[threadIdx.x >> 6] = s;
    __syncthreads();
    if (threadIdx.x == 0) bsums[blockIdx.x] = ws[0] + ws[1] + ws[2] + ws[3];
}

// exclusive scan of the 98 block sums (tiny, single thread) + rowPtr[NN]
__global__ void k_scan2(int* __restrict__ bsums, int* __restrict__ rowPtr, int nnz) {
    int acc = 0;
    for (int i = 0; i < SCAN_BLOCKS; ++i) {
        int t = bsums[i];
        bsums[i] = acc;
        acc += t;
    }
    rowPtr[NN] = nnz;
}

// per-block exclusive scan + global offset -> rowPtr, fillPos
__global__ __launch_bounds__(256) void k_scan3(const int* __restrict__ cnt,
                                               const int* __restrict__ bsums,
                                               int* __restrict__ rowPtr,
                                               int* __restrict__ fillPos) {
    int idx = blockIdx.x * SCAN_CHUNK + threadIdx.x * 4;
    int4 c = make_int4(0, 0, 0, 0);
    if (idx < NN) c = *(const int4*)(cnt + idx);
    int tsum = c.x + c.y + c.z + c.w;
    int lane = threadIdx.x & 63, w = threadIdx.x >> 6;
    int v = tsum;
#pragma unroll
    for (int m = 1; m < 64; m <<= 1) {
        int o = __shfl_up(v, m, 64);
        if (lane >= m) v += o;
    }
    __shared__ int wsum[4];
    if (lane == 63) wsum[w] = v;
    __syncthreads();
    int off = bsums[blockIdx.x];
    for (int i = 0; i < w; ++i) off += wsum[i];
    int excl = off + v - tsum;
    if (idx < NN) {
        int4 rp;
        rp.x = excl;
        rp.y = rp.x + c.x;
        rp.z = rp.y + c.y;
        rp.w = rp.z + c.z;
        *(int4*)(rowPtr + idx) = rp;
        *(int4*)(fillPos + idx) = rp;
    }
}

// scatter edges into CSR order; pack (col, val) in 8B
__global__ __launch_bounds__(256) void k_scatter(const int* __restrict__ rows,
                                                 const int* __restrict__ cols,
                                                 const float* __restrict__ vals,
                                                 int* __restrict__ fillPos,
                                                 int2* __restrict__ edges, int nnz) {
    int e = blockIdx.x * 256 + threadIdx.x;
    if (e >= nnz) return;
    int r = rows[e];
    int p = atomicAdd(&fillPos[r], 1);
    edges[p] = make_int2(cols[e], __float_as_int(vals[e]));
}

// ---------------------------------------------------------------- spmm ------
// one wave per row: Lx[r] = sum_e val_e * f[col_e]; float2/lane, no atomics
__global__ __launch_bounds__(256) void k_spmm_csr(const int* __restrict__ rowPtr,
                                                  const int2* __restrict__ edges,
                                                  const float* __restrict__ f,
                                                  float* __restrict__ Lx) {
    int r = blockIdx.x * 4 + (threadIdx.x >> 6);
    if (r >= NN) return;
    int lane = threadIdx.x & 63;
    int beg = rowPtr[r], end = rowPtr[r + 1];
    float2 acc = make_float2(0.f, 0.f);
    for (int e = beg; e < end; ++e) {
        int2 pk = edges[e];                     // wave-uniform broadcast load
        float v = __int_as_float(pk.y);
        float2 x = ((const float2*)(f + (size_t)pk.x * DD))[lane];
        acc.x = fmaf(v, x.x, acc.x);
        acc.y = fmaf(v, x.y, acc.y);
    }
    ((float2*)(Lx + (size_t)r * DD))[lane] = acc;
}

// ---------------------------------------------------------------- layer -----
#define BM 128
#define BN 128
#define BK 32
#define TM 8
#define TN 8

__global__ __launch_bounds__(256) void k_layer(const float* __restrict__ Lx,
                                               const float* __restrict__ feat,
                                               const float* __restrict__ Wlin,
                                               const float* __restrict__ blin,
                                               const float* __restrict__ Wint,
                                               const float* __restrict__ bint,
                                               float* __restrict__ fout) {
    __shared__ float As[BK][BM + 4];
    __shared__ float Bs[BK][BN];

    const int t  = threadIdx.x;
    const int tx = t & 15;
    const int ty = t >> 4;
    const int m0 = blockIdx.x * BM;

    float acc[TM][TN] = {};

    for (int kc = 0; kc < 8; ++kc) {
        const bool addhalf = (kc < 4);
        const int gk0 = addhalf ? kc * BK : (kc - 4) * BK;

#pragma unroll
        for (int p = 0; p < 4; ++p) {
            int idx4 = p * 256 + t;
            int ml = idx4 >> 3;
            int kk = (idx4 & 7) * 4;
            int gm = m0 + ml;
            float4 av;
            if (gm < NN) {
                float4 l4 = *(const float4*)(Lx   + (size_t)gm * DD + gk0 + kk);
                float4 f4 = *(const float4*)(feat + (size_t)gm * DD + gk0 + kk);
                if (addhalf)
                    av = make_float4(l4.x + f4.x, l4.y + f4.y, l4.z + f4.z, l4.w + f4.w);
                else
                    av = make_float4(l4.x * f4.x, l4.y * f4.y, l4.z * f4.z, l4.w * f4.w);
            } else {
                av = make_float4(0.f, 0.f, 0.f, 0.f);
            }
            As[kk + 0][ml] = av.x;
            As[kk + 1][ml] = av.y;
            As[kk + 2][ml] = av.z;
            As[kk + 3][ml] = av.w;
        }

        const float* Wsrc = addhalf ? Wlin : Wint;
#pragma unroll
        for (int p = 0; p < 4; ++p) {
            int k = p * 8 + (t >> 5);
            int j = (t & 31) * 4;
            *(float4*)&Bs[k][j] = *(const float4*)(Wsrc + (size_t)(gk0 + k) * DD + j);
        }

        __syncthreads();

#pragma unroll
        for (int kk = 0; kk < BK; ++kk) {
            float4 a0 = *(const float4*)&As[kk][ty * TM];
            float4 a1 = *(const float4*)&As[kk][ty * TM + 4];
            float4 b0 = *(const float4*)&Bs[kk][tx * TN];
            float4 b1 = *(const float4*)&Bs[kk][tx * TN + 4];
            float av[TM] = {a0.x, a0.y, a0.z, a0.w, a1.x, a1.y, a1.z, a1.w};
            float bv[TN] = {b0.x, b0.y, b0.z, b0.w, b1.x, b1.y, b1.z, b1.w};
#pragma unroll
            for (int i = 0; i < TM; ++i)
#pragma unroll
                for (int j = 0; j < TN; ++j)
                    acc[i][j] = fmaf(av[i], bv[j], acc[i][j]);
        }
        __syncthreads();
    }

    float bias[TN];
#pragma unroll
    for (int j = 0; j < TN; ++j) bias[j] = blin[tx * TN + j] + bint[tx * TN + j];

#pragma unroll
    for (int i = 0; i < TM; ++i) {
        float ss = 0.f;
#pragma unroll
        for (int j = 0; j < TN; ++j) {
            float v = acc[i][j] + bias[j];
            v = (v > 0.f) ? v : SLOPE_ * v;
            acc[i][j] = v;
            ss += v * v;
        }
#pragma unroll
        for (int m = 1; m < 16; m <<= 1) ss += __shfl_xor(ss, m, 64);
        float rinv = 1.0f / fmaxf(sqrtf(ss), EPS_);
        int gm = m0 + ty * TM + i;
        if (gm < NN) {
            float* op = fout + (size_t)gm * DD + tx * TN;
            *(float4*)op = make_float4(acc[i][0] * rinv, acc[i][1] * rinv,
                                       acc[i][2] * rinv, acc[i][3] * rinv);
            *(float4*)(op + 4) = make_float4(acc[i][4] * rinv, acc[i][5] * rinv,
                                             acc[i][6] * rinv, acc[i][7] * rinv);
        }
    }
}

// ---------------------------------------------------------------- launch ----
extern "C" void kernel_launch(void* const* d_in, const int* in_sizes, int n_in,
                              void* d_out, int out_size, void* d_ws, size_t ws_size,
                              hipStream_t stream) {
    const int*   userIdx = (const int*)d_in[0];
    const int*   itemIdx = (const int*)d_in[1];
    const int*   rows    = (const int*)d_in[2];
    const int*   cols    = (const int*)d_in[3];
    const float* vals    = (const float*)d_in[4];
    const float* uE      = (const float*)d_in[5];
    const float* iE      = (const float*)d_in[6];
    const float* Wlin    = (const float*)d_in[7];
    const float* blin    = (const float*)d_in[8];
    const float* Wint    = (const float*)d_in[9];
    const float* bint    = (const float*)d_in[10];
    float* out = (float*)d_out;

    const int batch = in_sizes[0];
    const int nnz   = in_sizes[2];

    // ---- workspace layout (all 16B aligned) ----
    float* feat    = (float*)d_ws;                    // 51.2 MB
    float* Lx      = feat + (size_t)NN * DD;          // 51.2 MB
    int*   cnt     = (int*)(Lx + (size_t)NN * DD);    // 400 KB
    int*   rowPtr  = cnt + NN;                        // (NN+4) ints
    int*   fillPos = rowPtr + NN + 4;                 // 400 KB
    int*   bsums   = fillPos + NN;                    // 512 B
    int2*  edges   = (int2*)(bsums + 128);            // 8 MB

    const int total4 = NN * (DD / 4);
    const int nu4    = NU * (DD / 4);

    // features = concat(uEmbd, iEmbd)
    k_concat<<<(total4 + 255) / 256, 256, 0, stream>>>(
        (const float4*)uE, (const float4*)iE, (float4*)feat, total4, nu4);

    // ---- build CSR once per launch ----
    k_zero<<<(NN / 4 + 255) / 256, 256, 0, stream>>>((float4*)cnt, NN / 4);
    k_hist<<<(nnz + 255) / 256, 256, 0, stream>>>(rows, cnt, nnz);
    k_scan1<<<SCAN_BLOCKS, 256, 0, stream>>>(cnt, bsums);
    k_scan2<<<1, 1, 0, stream>>>(bsums, rowPtr, nnz);
    k_scan3<<<SCAN_BLOCKS, 256, 0, stream>>>(cnt, bsums, rowPtr, fillPos);
    k_scatter<<<(nnz + 255) / 256, 256, 0, stream>>>(rows, cols, vals, fillPos, edges, nnz);

    // layer-0 dot
    k_dot<<<(batch + 3) / 4, 256, 0, stream>>>(feat, userIdx, itemIdx, out, batch, 0);

    for (int l = 0; l < NLAYERS; ++l) {
        k_spmm_csr<<<(NN + 3) / 4, 256, 0, stream>>>(rowPtr, edges, feat, Lx);
        k_layer<<<(NN + BM - 1) / BM, 256, 0, stream>>>(
            Lx, feat,
            Wlin + (size_t)l * DD * DD, blin + (size_t)l * DD,
            Wint + (size_t)l * DD * DD, bint + (size_t)l * DD,
            feat);
        k_dot<<<(batch + 3) / 4, 256, 0, stream>>>(feat, userIdx, itemIdx, out, batch, 1);
    }
}

// Round 3
// 546.060 us; speedup vs baseline: 5.4183x; 1.6793x over previous
//
#include <hip/hip_runtime.h>
#include <hip/hip_bf16.h>

#define NU 30000
#define NI 70000
#define NN 100000
#define DD 128
#define NLAYERS 3
#define SLOPE_ 0.01f
#define EPS_ 1e-12f

#define SCAN_CHUNK 1024
#define SCAN_BLOCKS ((NN + SCAN_CHUNK - 1) / SCAN_CHUNK)   // 98

typedef __bf16 v8bf __attribute__((ext_vector_type(8)));
typedef float v16f __attribute__((ext_vector_type(16)));
typedef unsigned short ushort_t;

union U8 { ushort_t s[8]; uint4 u; v8bf v; };

__device__ __forceinline__ float bf2f(unsigned v) {      // low 16 bits = bf16
    return __uint_as_float(v << 16);
}
__device__ __forceinline__ ushort_t f2bf(float x) {      // RNE
    unsigned u = __float_as_uint(x);
    u += 0x7FFF + ((u >> 16) & 1);
    return (ushort_t)(u >> 16);
}
__device__ __forceinline__ void unp8(uint4 g, float* f) {
    f[0] = bf2f(g.x & 0xffff); f[1] = bf2f(g.x >> 16);
    f[2] = bf2f(g.y & 0xffff); f[3] = bf2f(g.y >> 16);
    f[4] = bf2f(g.z & 0xffff); f[5] = bf2f(g.z >> 16);
    f[6] = bf2f(g.w & 0xffff); f[7] = bf2f(g.w >> 16);
}
__device__ __forceinline__ uint4 pk8(const float* f) {
    uint4 g;
    g.x = (unsigned)f2bf(f[0]) | ((unsigned)f2bf(f[1]) << 16);
    g.y = (unsigned)f2bf(f[2]) | ((unsigned)f2bf(f[3]) << 16);
    g.z = (unsigned)f2bf(f[4]) | ((unsigned)f2bf(f[5]) << 16);
    g.w = (unsigned)f2bf(f[6]) | ((unsigned)f2bf(f[7]) << 16);
    return g;
}

// ---------------------------------------------------------------- concat ----
// fp32 embeds -> bf16 features
__global__ __launch_bounds__(256) void k_concat_bf(const float* __restrict__ u,
                                                   const float* __restrict__ it,
                                                   ushort_t* __restrict__ fb) {
    int idx = blockIdx.x * 256 + threadIdx.x;       // chunk of 8 elems
    if (idx >= NN * DD / 8) return;
    size_t base = (size_t)idx * 8;
    const float* src = (base < (size_t)NU * DD) ? (u + base) : (it + base - (size_t)NU * DD);
    float f[8];
    float4 a = *(const float4*)src;
    float4 b = *(const float4*)(src + 4);
    f[0] = a.x; f[1] = a.y; f[2] = a.z; f[3] = a.w;
    f[4] = b.x; f[5] = b.y; f[6] = b.z; f[7] = b.w;
    *(uint4*)(fb + base) = pk8(f);
}

// ---------------------------------------------------------------- zero ------
__global__ __launch_bounds__(256) void k_zero(float4* __restrict__ p, int n4) {
    int i = blockIdx.x * 256 + threadIdx.x;
    if (i < n4) p[i] = make_float4(0.f, 0.f, 0.f, 0.f);
}

// ---------------------------------------------------------------- dot -------
__global__ __launch_bounds__(256) void k_dot(const ushort_t* __restrict__ fb,
                                             const int* __restrict__ uIdx,
                                             const int* __restrict__ iIdx,
                                             float* __restrict__ out,
                                             int batch, int accum) {
    int b = blockIdx.x * 4 + (threadIdx.x >> 6);
    if (b >= batch) return;
    int lane = threadIdx.x & 63;
    unsigned ua = *(const unsigned*)(fb + (size_t)uIdx[b] * DD + lane * 2);
    unsigned ib = *(const unsigned*)(fb + (size_t)(iIdx[b] + NU) * DD + lane * 2);
    float s = bf2f(ua & 0xffff) * bf2f(ib & 0xffff) + bf2f(ua >> 16) * bf2f(ib >> 16);
#pragma unroll
    for (int m = 32; m; m >>= 1) s += __shfl_xor(s, m, 64);
    if (lane == 0) out[b] = accum ? out[b] + s : s;
}

// ---------------------------------------------------------------- CSR build -
__global__ __launch_bounds__(256) void k_hist(const int* __restrict__ rows,
                                              int* __restrict__ cnt, int nnz) {
    int e = blockIdx.x * 256 + threadIdx.x;
    if (e < nnz) atomicAdd(&cnt[rows[e]], 1);
}

__global__ __launch_bounds__(256) void k_scan1(const int* __restrict__ cnt,
                                               int* __restrict__ bsums) {
    int idx = blockIdx.x * SCAN_CHUNK + threadIdx.x * 4;
    int4 c = make_int4(0, 0, 0, 0);
    if (idx < NN) c = *(const int4*)(cnt + idx);
    int s = c.x + c.y + c.z + c.w;
#pragma unroll
    for (int m = 1; m < 64; m <<= 1) s += __shfl_xor(s, m, 64);
    __shared__ int ws[4];
    if ((threadIdx.x & 63) == 0) ws[threadIdx.x >> 6] = s;
    __syncthreads();
    if (threadIdx.x == 0) bsums[blockIdx.x] = ws[0] + ws[1] + ws[2] + ws[3];
}

__global__ void k_scan2(int* __restrict__ bsums, int* __restrict__ rowPtr, int nnz) {
    int acc = 0;
    for (int i = 0; i < SCAN_BLOCKS; ++i) {
        int t = bsums[i];
        bsums[i] = acc;
        acc += t;
    }
    rowPtr[NN] = nnz;
}

__global__ __launch_bounds__(256) void k_scan3(const int* __restrict__ cnt,
                                               const int* __restrict__ bsums,
                                               int* __restrict__ rowPtr,
                                               int* __restrict__ fillPos) {
    int idx = blockIdx.x * SCAN_CHUNK + threadIdx.x * 4;
    int4 c = make_int4(0, 0, 0, 0);
    if (idx < NN) c = *(const int4*)(cnt + idx);
    int tsum = c.x + c.y + c.z + c.w;
    int lane = threadIdx.x & 63, w = threadIdx.x >> 6;
    int v = tsum;
#pragma unroll
    for (int m = 1; m < 64; m <<= 1) {
        int o = __shfl_up(v, m, 64);
        if (lane >= m) v += o;
    }
    __shared__ int wsum[4];
    if (lane == 63) wsum[w] = v;
    __syncthreads();
    int off = bsums[blockIdx.x];
    for (int i = 0; i < w; ++i) off += wsum[i];
    int excl = off + v - tsum;
    if (idx < NN) {
        int4 rp;
        rp.x = excl;
        rp.y = rp.x + c.x;
        rp.z = rp.y + c.y;
        rp.w = rp.z + c.z;
        *(int4*)(rowPtr + idx) = rp;
        *(int4*)(fillPos + idx) = rp;
    }
}

__global__ __launch_bounds__(256) void k_scatter(const int* __restrict__ rows,
                                                 const int* __restrict__ cols,
                                                 const float* __restrict__ vals,
                                                 int* __restrict__ fillPos,
                                                 int2* __restrict__ edges, int nnz) {
    int e = blockIdx.x * 256 + threadIdx.x;
    if (e >= nnz) return;
    int r = rows[e];
    int p = atomicAdd(&fillPos[r], 1);
    edges[p] = make_int2(cols[e], __float_as_int(vals[e]));
}

// ---------------------------------------------------------------- spmm ------
// one wave per row; 4 quarter-waves process 4 edges concurrently;
// each lane covers 8 dims (16B bf16 gather); fp32 accumulate; bf16 store.
__global__ __launch_bounds__(256) void k_spmm_bf(const int* __restrict__ rowPtr,
                                                 const int2* __restrict__ edges,
                                                 const ushort_t* __restrict__ fb,
                                                 ushort_t* __restrict__ Lxb) {
    int r = blockIdx.x * 4 + (threadIdx.x >> 6);
    if (r >= NN) return;
    int l = threadIdx.x & 63;
    int q = l >> 4;           // quarter 0..3
    int d0 = (l & 15) * 8;    // dim base
    int beg = rowPtr[r], end = rowPtr[r + 1];
    float acc[8] = {0.f, 0.f, 0.f, 0.f, 0.f, 0.f, 0.f, 0.f};
    for (int e = beg + q; e < end; e += 4) {
        int2 pk = edges[e];
        float v = __int_as_float(pk.y);
        uint4 g = *(const uint4*)(fb + (size_t)pk.x * DD + d0);
        float x[8];
        unp8(g, x);
#pragma unroll
        for (int j = 0; j < 8; ++j) acc[j] = fmaf(v, x[j], acc[j]);
    }
#pragma unroll
    for (int j = 0; j < 8; ++j) {
        acc[j] += __shfl_xor(acc[j], 16, 64);
        acc[j] += __shfl_xor(acc[j], 32, 64);
    }
    if (l < 16) *(uint4*)(Lxb + (size_t)r * DD + d0) = pk8(acc);
}

// ---------------------------------------------------------------- layer -----
// MFMA bf16: A = [Lx+f | Lx*f] (M x 256) staged in LDS; B = [Wlin;Wint]
// (256 x 128) held as 16 register fragments per wave (wave owns 32 cols).
// Block: 256 thr = 4 waves, BM = 128 (4 m-tiles of 32), v_mfma_f32_32x32x16_bf16.
#define AST 264   // LDS A row stride in bf16 elems (256 + 8 pad)

__global__ __launch_bounds__(256) void k_layer_mfma(const ushort_t* __restrict__ Lxb,
                                                    const float* __restrict__ Wlin,
                                                    const float* __restrict__ blin,
                                                    const float* __restrict__ Wint,
                                                    const float* __restrict__ bint,
                                                    ushort_t* __restrict__ fb) {
    __shared__ ushort_t As[128 * AST];   // 67584 B
    __shared__ float pnorm[32 * 4];      // [row][wave]

    const int t = threadIdx.x;
    const int w = t >> 6;       // wave 0..3 -> owns cols 32w..32w+31
    const int l = t & 63;
    const int q = l >> 5;       // half-wave
    const int ln = l & 31;
    const int n = w * 32 + ln;  // global output col
    const int m0 = blockIdx.x * 128;

    // ---- stage A into LDS (add-half at k=0..127, mul-half at k=128..255) ----
#pragma unroll
    for (int ii = 0; ii < 8; ++ii) {
        int idx = ii * 256 + t;         // 0..2047
        int row = idx >> 4;             // 0..127
        int c = idx & 15;               // 8-dim chunk
        int gm = m0 + row;
        float fa[8], fm[8];
        if (gm < NN) {
            float lx[8], ff[8];
            unp8(*(const uint4*)(Lxb + (size_t)gm * DD + c * 8), lx);
            unp8(*(const uint4*)(fb  + (size_t)gm * DD + c * 8), ff);
#pragma unroll
            for (int j = 0; j < 8; ++j) { fa[j] = lx[j] + ff[j]; fm[j] = lx[j] * ff[j]; }
        } else {
#pragma unroll
            for (int j = 0; j < 8; ++j) { fa[j] = 0.f; fm[j] = 0.f; }
        }
        *(uint4*)&As[row * AST + c * 8]       = pk8(fa);
        *(uint4*)&As[row * AST + 128 + c * 8] = pk8(fm);
    }

    // ---- B fragments: lane holds B[k = 16s + 8q + j][n], j=0..7, s=0..15 ----
    v8bf bfrag[16];
#pragma unroll
    for (int s = 0; s < 16; ++s) {
        U8 tmp;
#pragma unroll
        for (int j = 0; j < 8; ++j) {
            int k = s * 16 + q * 8 + j;
            float wv = (k < 128) ? Wlin[(size_t)k * DD + n]
                                 : Wint[(size_t)(k - 128) * DD + n];
            tmp.s[j] = f2bf(wv);
        }
        bfrag[s] = tmp.v;
    }

    const float bias = blin[n] + bint[n];

    __syncthreads();

    // ---- 4 m-tiles of 32 rows ----
    for (int mt = 0; mt < 4; ++mt) {
        v16f acc;
#pragma unroll
        for (int i = 0; i < 16; ++i) acc[i] = 0.f;

#pragma unroll
        for (int s = 0; s < 16; ++s) {
            v8bf af = *(const v8bf*)&As[(mt * 32 + ln) * AST + s * 16 + q * 8];
            acc = __builtin_amdgcn_mfma_f32_32x32x16_bf16(af, bfrag[s], acc, 0, 0, 0);
        }

        // epilogue: bias + leakyrelu, per-row sumsq partial (this wave's 32 cols)
        float vv[16], ss[16];
#pragma unroll
        for (int reg = 0; reg < 16; ++reg) {
            float v = acc[reg] + bias;
            v = (v > 0.f) ? v : SLOPE_ * v;
            vv[reg] = v;
            float s2 = v * v;
#pragma unroll
            for (int m = 1; m < 32; m <<= 1) s2 += __shfl_xor(s2, m, 64);
            ss[reg] = s2;   // all lanes of half-wave hold row sum over 32 cols
        }
        if (ln == 0) {
#pragma unroll
            for (int reg = 0; reg < 16; ++reg) {
                int row = (reg & 3) + 8 * (reg >> 2) + 4 * q;
                pnorm[row * 4 + w] = ss[reg];
            }
        }
        __syncthreads();

#pragma unroll
        for (int reg = 0; reg < 16; ++reg) {
            int row = (reg & 3) + 8 * (reg >> 2) + 4 * q;
            float4 p = *(const float4*)&pnorm[row * 4];
            float tot = p.x + p.y + p.z + p.w;
            float rinv = 1.0f / fmaxf(sqrtf(tot), EPS_);
            int gm = m0 + mt * 32 + row;
            if (gm < NN) fb[(size_t)gm * DD + n] = f2bf(vv[reg] * rinv);
        }
        __syncthreads();   // protect pnorm before next m-tile
    }
}

// ---------------------------------------------------------------- launch ----
extern "C" void kernel_launch(void* const* d_in, const int* in_sizes, int n_in,
                              void* d_out, int out_size, void* d_ws, size_t ws_size,
                              hipStream_t stream) {
    const int*   userIdx = (const int*)d_in[0];
    const int*   itemIdx = (const int*)d_in[1];
    const int*   rows    = (const int*)d_in[2];
    const int*   cols    = (const int*)d_in[3];
    const float* vals    = (const float*)d_in[4];
    const float* uE      = (const float*)d_in[5];
    const float* iE      = (const float*)d_in[6];
    const float* Wlin    = (const float*)d_in[7];
    const float* blin    = (const float*)d_in[8];
    const float* Wint    = (const float*)d_in[9];
    const float* bint    = (const float*)d_in[10];
    float* out = (float*)d_out;

    const int batch = in_sizes[0];
    const int nnz   = in_sizes[2];

    // ---- workspace layout ----
    ushort_t* featb = (ushort_t*)d_ws;                       // 25.6 MB
    ushort_t* Lxb   = featb + (size_t)NN * DD;               // 25.6 MB
    int*   cnt     = (int*)(Lxb + (size_t)NN * DD);          // 400 KB
    int*   rowPtr  = cnt + NN;
    int*   fillPos = rowPtr + NN + 4;
    int*   bsums   = fillPos + NN;
    int2*  edges   = (int2*)(bsums + 128);                   // 8 MB

    k_concat_bf<<<(NN * DD / 8 + 255) / 256, 256, 0, stream>>>(uE, iE, featb);

    // ---- CSR build ----
    k_zero<<<(NN / 4 + 255) / 256, 256, 0, stream>>>((float4*)cnt, NN / 4);
    k_hist<<<(nnz + 255) / 256, 256, 0, stream>>>(rows, cnt, nnz);
    k_scan1<<<SCAN_BLOCKS, 256, 0, stream>>>(cnt, bsums);
    k_scan2<<<1, 1, 0, stream>>>(bsums, rowPtr, nnz);
    k_scan3<<<SCAN_BLOCKS, 256, 0, stream>>>(cnt, bsums, rowPtr, fillPos);
    k_scatter<<<(nnz + 255) / 256, 256, 0, stream>>>(rows, cols, vals, fillPos, edges, nnz);

    k_dot<<<(batch + 3) / 4, 256, 0, stream>>>(featb, userIdx, itemIdx, out, batch, 0);

    for (int l = 0; l < NLAYERS; ++l) {
        k_spmm_bf<<<(NN + 3) / 4, 256, 0, stream>>>(rowPtr, edges, featb, Lxb);
        k_layer_mfma<<<(NN + 127) / 128, 256, 0, stream>>>(
            Lxb,
            Wlin + (size_t)l * DD * DD, blin + (size_t)l * DD,
            Wint + (size_t)l * DD * DD, bint + (size_t)l * DD,
            featb);
        k_dot<<<(batch + 3) / 4, 256, 0, stream>>>(featb, userIdx, itemIdx, out, batch, 1);
    }
}